// Round 1
// baseline (1106.171 us; speedup 1.0000x reference)
//
#include <hip/hip_runtime.h>
#include <hip/hip_bf16.h>

#define HCONC 128   // H*C
#define NHEAD 4
#define CCH   32
#define EDIM  8
#define NREL  16

// ---------------------------------------------------------------------------
// Relation histogram (for mean edge_attr used by self-loop fill)
__global__ void hist_kernel(const int* __restrict__ etype, int E, int* __restrict__ cnt) {
    __shared__ int lcnt[NREL];
    if (threadIdx.x < NREL) lcnt[threadIdx.x] = 0;
    __syncthreads();
    for (int i = blockIdx.x * blockDim.x + threadIdx.x; i < E; i += gridDim.x * blockDim.x)
        atomicAdd(&lcnt[etype[i]], 1);
    __syncthreads();
    if (threadIdx.x < NREL) atomicAdd(&cnt[threadIdx.x], lcnt[threadIdx.x]);
}

// ---------------------------------------------------------------------------
// One-block setup: W0 colsum, mean edge attr, layer-0 score consts, s_edge tables
__global__ void setup_kernel(const float* __restrict__ W_l0, const float* __restrict__ emb,
                             const int* __restrict__ cnt,
                             const float* __restrict__ att_src, const float* __restrict__ att_dst,
                             const float* __restrict__ att_edge, const float* __restrict__ W_edge,
                             float* __restrict__ W0s, float* __restrict__ SA0, float* __restrict__ SD0,
                             float* __restrict__ meanat, float* __restrict__ stab, int E) {
    int t = threadIdx.x;
    if (t < HCONC) {
        float s = 0.f;
        for (int k = 0; k < CCH; k++) s += W_l0[k * HCONC + t];
        W0s[t] = s;
    }
    __syncthreads();
    if (t < EDIM) {
        float s = 0.f;
        for (int r = 0; r < NREL; r++) s += (float)cnt[r] * emb[r * EDIM + t];
        meanat[t] = s / (float)E;
    }
    __syncthreads();
    if (t < NHEAD) {
        float sa = 0.f, sd = 0.f;
        for (int c = 0; c < CCH; c++) {
            sa += W0s[t * CCH + c] * att_src[t * CCH + c];
            sd += W0s[t * CCH + c] * att_dst[t * CCH + c];
        }
        SA0[t] = sa; SD0[t] = sd;
    }
    if (t < 3 * 68) {  // 3 layers x 17 types x 4 heads
        int l = t / 68, rem = t % 68, typ = rem >> 2, hh = rem & 3;
        const float* attr = (typ < NREL) ? &emb[typ * EDIM] : meanat;
        const float* We = W_edge + l * EDIM * HCONC;
        const float* ae = att_edge + l * HCONC + hh * CCH;
        float s = 0.f;
        for (int c = 0; c < CCH; c++) {
            float ev = 0.f;
            for (int d = 0; d < EDIM; d++) ev += attr[d] * We[d * HCONC + hh * CCH + c];
            s += ev * ae[c];
        }
        stab[t] = s;  // stab[l*68 + typ*4 + hh]
    }
}

// ---------------------------------------------------------------------------
// CSR build: degree count (incl self loops), 2-level scan, scatter
__global__ void deg_kernel(const int* __restrict__ ei, int E, int n, int* __restrict__ deg) {
    int total = E + n;
    for (int i = blockIdx.x * blockDim.x + threadIdx.x; i < total; i += gridDim.x * blockDim.x) {
        int d = (i < E) ? ei[E + i] : (i - E);
        atomicAdd(&deg[d], 1);
    }
}

__global__ void scan1(const int* __restrict__ deg, int n, int* __restrict__ row_ptr,
                      int* __restrict__ partials) {
    __shared__ int tmp[1024];
    int t = threadIdx.x, i = blockIdx.x * 1024 + t;
    int v = (i < n) ? deg[i] : 0;
    tmp[t] = v;
    __syncthreads();
    for (int off = 1; off < 1024; off <<= 1) {
        int add = (t >= off) ? tmp[t - off] : 0;
        __syncthreads();
        tmp[t] += add;
        __syncthreads();
    }
    if (i < n) row_ptr[i] = tmp[t] - v;          // exclusive, block-local
    if (t == 1023) partials[blockIdx.x] = tmp[1023];
}

__global__ void scan2(int* __restrict__ partials, int nb, int* __restrict__ row_ptr, int n) {
    if (threadIdx.x == 0 && blockIdx.x == 0) {
        int run = 0;
        for (int b = 0; b < nb; b++) { int v = partials[b]; partials[b] = run; run += v; }
        row_ptr[n] = run;
    }
}

__global__ void scan3(int* __restrict__ row_ptr, int n, const int* __restrict__ partials,
                      int* __restrict__ cursor) {
    int i = blockIdx.x * 1024 + threadIdx.x;
    if (i < n) {
        int r = row_ptr[i] + partials[blockIdx.x];
        row_ptr[i] = r;
        cursor[i] = r;
    }
}

__global__ void scatter_kernel(const int* __restrict__ ei, const int* __restrict__ etype,
                               int E, int n, int* __restrict__ cursor, unsigned* __restrict__ col) {
    int total = E + n;
    for (int i = blockIdx.x * blockDim.x + threadIdx.x; i < total; i += gridDim.x * blockDim.x) {
        int d; unsigned p;
        if (i < E) { d = ei[E + i]; p = (unsigned)ei[i] | ((unsigned)etype[i] << 16); }
        else       { int nd = i - E; d = nd; p = (unsigned)nd | (16u << 16); }
        int pos = atomicAdd(&cursor[d], 1);
        col[pos] = p;
    }
}

// ---------------------------------------------------------------------------
// Layer-0 rank-1 transform: h0 = x * colsum(W0), s = x * const
__global__ void l0h_kernel(const float* __restrict__ x, const float* __restrict__ W0s,
                           float* __restrict__ h, int n) {
    int idx = blockIdx.x * blockDim.x + threadIdx.x;
    if (idx < n * HCONC) h[idx] = x[idx >> 7] * W0s[idx & 127];
}

__global__ void l0s_kernel(const float* __restrict__ x, const float* __restrict__ SA0,
                           const float* __restrict__ SD0, float* __restrict__ s_src,
                           float* __restrict__ s_dst, int n) {
    int idx = blockIdx.x * blockDim.x + threadIdx.x;
    if (idx < n * NHEAD) {
        float xv = x[idx >> 2];
        int hh = idx & 3;
        s_src[idx] = xv * SA0[hh];
        s_dst[idx] = xv * SD0[hh];
    }
}

// ---------------------------------------------------------------------------
// Dense transform h = X @ W (128x128) + fused attention score reduction.
// 4 waves/block, 8 rows/wave, lane covers cols (lane, lane+64).
__global__ __launch_bounds__(256) void transform_kernel(
    const float* __restrict__ X, const float* __restrict__ W,
    const float* __restrict__ a_src, const float* __restrict__ a_dst,
    float* __restrict__ h_out, float* __restrict__ s_src, float* __restrict__ s_dst, int n) {
    int lane = threadIdx.x & 63;
    int wv = threadIdx.x >> 6;
    int row_base = __builtin_amdgcn_readfirstlane(blockIdx.x * 32 + wv * 8);

    const float4* xp[8];
#pragma unroll
    for (int r = 0; r < 8; r++) {
        int row = row_base + r;
        if (row >= n) row = n - 1;
        xp[r] = (const float4*)(X + (size_t)row * HCONC);
    }

    float acc0[8], acc1[8];
#pragma unroll
    for (int r = 0; r < 8; r++) { acc0[r] = 0.f; acc1[r] = 0.f; }

    for (int k4 = 0; k4 < 32; k4++) {
        float4 xv[8];
#pragma unroll
        for (int r = 0; r < 8; r++) xv[r] = xp[r][k4];
#pragma unroll
        for (int j = 0; j < 4; j++) {
            int k = k4 * 4 + j;
            float w0 = W[k * HCONC + lane];
            float w1 = W[k * HCONC + 64 + lane];
#pragma unroll
            for (int r = 0; r < 8; r++) {
                float x_s = (j == 0) ? xv[r].x : (j == 1) ? xv[r].y : (j == 2) ? xv[r].z : xv[r].w;
                acc0[r] = fmaf(x_s, w0, acc0[r]);
                acc1[r] = fmaf(x_s, w1, acc1[r]);
            }
        }
    }

    float aS0 = a_src[lane], aS1 = a_src[lane + 64];
    float aD0 = a_dst[lane], aD1 = a_dst[lane + 64];

#pragma unroll
    for (int r = 0; r < 8; r++) {
        int row = row_base + r;
        float ts0 = acc0[r] * aS0, ts1 = acc1[r] * aS1;
        float td0 = acc0[r] * aD0, td1 = acc1[r] * aD1;
#pragma unroll
        for (int off = 1; off <= 16; off <<= 1) {
            ts0 += __shfl_xor(ts0, off);
            ts1 += __shfl_xor(ts1, off);
            td0 += __shfl_xor(td0, off);
            td1 += __shfl_xor(td1, off);
        }
        if (row < n) {
            h_out[(size_t)row * HCONC + lane] = acc0[r];
            h_out[(size_t)row * HCONC + 64 + lane] = acc1[r];
            if (lane == 0) {
                s_src[row * 4 + 0] = ts0; s_src[row * 4 + 2] = ts1;
                s_dst[row * 4 + 0] = td0; s_dst[row * 4 + 2] = td1;
            }
            if (lane == 32) {
                s_src[row * 4 + 1] = ts0; s_src[row * 4 + 3] = ts1;
                s_dst[row * 4 + 1] = td0; s_dst[row * 4 + 3] = td1;
            }
        }
    }
}

// ---------------------------------------------------------------------------
// Softmax-aggregation: one wave per dst node, two passes over its edge list.
// Lane covers channels (lane -> head lane>>5, lane+64 -> head 2+(lane>>5)).
__global__ __launch_bounds__(256) void agg_kernel(
    const float* __restrict__ h, const float* __restrict__ s_src, const float* __restrict__ s_dst,
    const int* __restrict__ row_ptr, const unsigned* __restrict__ col,
    const float* __restrict__ tab, const float* __restrict__ bias,
    const float* __restrict__ x_prev, float* __restrict__ x_out, int n) {
    __shared__ float stab_s[68];
    if (threadIdx.x < 68) stab_s[threadIdx.x] = tab[threadIdx.x];
    __syncthreads();

    int d = __builtin_amdgcn_readfirstlane(blockIdx.x * 4 + (threadIdx.x >> 6));
    if (d >= n) return;
    int lane = threadIdx.x & 63;
    int hsel = lane >> 5;  // 0/1 -> heads (hsel, hsel+2)

    int start = row_ptr[d], end = row_ptr[d + 1];
    float4 sd = *(const float4*)&s_dst[d * 4];
    float sdA = hsel ? sd.y : sd.x;
    float sdB = hsel ? sd.w : sd.z;

    // pass A: per-head max of leaky-relu scores
    float mA = -1e30f, mB = -1e30f;
    for (int e = start; e < end; e++) {
        unsigned p = col[e];
        int src = p & 0xFFFF;
        int typ = p >> 16;
        float4 ss = *(const float4*)&s_src[src * 4];
        float sA = (hsel ? ss.y : ss.x) + sdA + stab_s[typ * 4 + hsel];
        float sB = (hsel ? ss.w : ss.z) + sdB + stab_s[typ * 4 + 2 + hsel];
        sA = sA > 0.f ? sA : 0.2f * sA;
        sB = sB > 0.f ? sB : 0.2f * sB;
        mA = fmaxf(mA, sA);
        mB = fmaxf(mB, sB);
    }

    // pass B: unnormalized weighted sum + denominator
    float denA = 0.f, denB = 0.f, acc0 = 0.f, acc1 = 0.f;
    for (int e = start; e < end; e++) {
        unsigned p = col[e];
        int src = p & 0xFFFF;
        int typ = p >> 16;
        float4 ss = *(const float4*)&s_src[src * 4];
        float sA = (hsel ? ss.y : ss.x) + sdA + stab_s[typ * 4 + hsel];
        float sB = (hsel ? ss.w : ss.z) + sdB + stab_s[typ * 4 + 2 + hsel];
        sA = sA > 0.f ? sA : 0.2f * sA;
        sB = sB > 0.f ? sB : 0.2f * sB;
        float wA = __expf(sA - mA);
        float wB = __expf(sB - mB);
        denA += wA; denB += wB;
        const float* hr = h + (size_t)src * HCONC;
        acc0 = fmaf(wA, hr[lane], acc0);
        acc1 = fmaf(wB, hr[lane + 64], acc1);
    }

    float o0 = acc0 / (denA + 1e-16f) + bias[lane];
    float o1 = acc1 / (denB + 1e-16f) + bias[lane + 64];
    if (x_prev) {
        o0 += x_prev[(size_t)d * HCONC + lane];
        o1 += x_prev[(size_t)d * HCONC + 64 + lane];
    }
    o0 = fmaxf(o0, 0.f);
    o1 = fmaxf(o1, 0.f);
    x_out[(size_t)d * HCONC + lane] = o0;
    x_out[(size_t)d * HCONC + 64 + lane] = o1;
}

// ---------------------------------------------------------------------------
// MLP head: relu(x@W1+b1) @ W2 + b2 -> sigmoid.  4 nodes per 128-thread block.
__global__ __launch_bounds__(128) void mlp_kernel(
    const float* __restrict__ X, const float* __restrict__ W1, const float* __restrict__ b1,
    const float* __restrict__ W2, const float* __restrict__ b2, float* __restrict__ out, int n) {
    __shared__ float xs[4][HCONC];
    __shared__ float red[4][128];
    int t = threadIdx.x;
    int base = blockIdx.x * 4;
#pragma unroll
    for (int nn = 0; nn < 4; nn++) {
        int row = base + nn;
        xs[nn][t] = (row < n) ? X[(size_t)row * HCONC + t] : 0.f;
    }
    __syncthreads();
    float p[4] = {0.f, 0.f, 0.f, 0.f};
    if (t < 100) {
        float w2 = W2[t];
#pragma unroll
        for (int nn = 0; nn < 4; nn++) {
            float a = b1[t];
            for (int k = 0; k < HCONC; k++) a = fmaf(xs[nn][k], W1[k * 100 + t], a);
            a = fmaxf(a, 0.f);
            p[nn] = a * w2;
        }
    }
#pragma unroll
    for (int nn = 0; nn < 4; nn++) red[nn][t] = p[nn];
    __syncthreads();
    for (int s = 64; s > 0; s >>= 1) {
        if (t < s) {
#pragma unroll
            for (int nn = 0; nn < 4; nn++) red[nn][t] += red[nn][t + s];
        }
        __syncthreads();
    }
    if (t < 4) {
        int row = base + t;
        if (row < n) out[row] = 1.f / (1.f + __expf(-(red[t][0] + b2[0])));
    }
}

// ---------------------------------------------------------------------------
extern "C" void kernel_launch(void* const* d_in, const int* in_sizes, int n_in,
                              void* d_out, int out_size, void* d_ws, size_t ws_size,
                              hipStream_t stream) {
    const float* x       = (const float*)d_in[0];
    const int*   ei      = (const int*)d_in[1];     // [2,E]: src then dst
    const int*   etype   = (const int*)d_in[2];
    const float* emb     = (const float*)d_in[3];   // [16,8]
    const float* W_l0    = (const float*)d_in[4];   // [32,128]
    const float* W_l1    = (const float*)d_in[5];   // [128,128]
    const float* W_l2    = (const float*)d_in[6];   // [128,128]
    const float* att_src = (const float*)d_in[7];   // [3,4,32]
    const float* att_dst = (const float*)d_in[8];
    const float* att_edge= (const float*)d_in[9];
    const float* W_edge  = (const float*)d_in[10];  // [3,8,128]
    const float* bias    = (const float*)d_in[11];  // [3,128]
    const float* mW1     = (const float*)d_in[12];  // [128,100]
    const float* mb1     = (const float*)d_in[13];
    const float* mW2     = (const float*)d_in[14];  // [100,1]
    const float* mb2     = (const float*)d_in[15];

    int n = in_sizes[0];   // 50000
    int E = in_sizes[2];   // 800000

    // workspace carve
    float* p   = (float*)d_ws;
    float* xa  = p; p += (size_t)n * HCONC;
    float* xb  = p; p += (size_t)n * HCONC;
    float* hb  = p; p += (size_t)n * HCONC;
    float* ssrc = p; p += (size_t)n * NHEAD;
    float* sdst = p; p += (size_t)n * NHEAD;
    int* deg      = (int*)p;
    int* row_ptr  = deg + n;
    int* cursor   = row_ptr + n + 1;
    int* partials = cursor + n;      // 64
    int* cnt      = partials + 64;   // 16
    float* W0s    = (float*)(cnt + 16);
    float* SA0    = W0s + HCONC;
    float* SD0    = SA0 + NHEAD;
    float* meanat = SD0 + NHEAD;
    float* stab   = meanat + EDIM;   // 3*68 = 204, round to 256
    unsigned* col = (unsigned*)(stab + 256);  // E+n entries

    // zero the metadata region (deg..cnt) — ws is poisoned 0xAA by harness
    size_t zero_bytes = (size_t)((char*)(cnt + 16) - (char*)deg);
    hipMemsetAsync(deg, 0, zero_bytes, stream);

    hist_kernel<<<256, 256, 0, stream>>>(etype, E, cnt);
    setup_kernel<<<1, 256, 0, stream>>>(W_l0, emb, cnt, att_src, att_dst, att_edge, W_edge,
                                        W0s, SA0, SD0, meanat, stab, E);
    deg_kernel<<<512, 256, 0, stream>>>(ei, E, n, deg);
    int nb_scan = (n + 1023) / 1024;
    scan1<<<nb_scan, 1024, 0, stream>>>(deg, n, row_ptr, partials);
    scan2<<<1, 1, 0, stream>>>(partials, nb_scan, row_ptr, n);
    scan3<<<nb_scan, 1024, 0, stream>>>(row_ptr, n, partials, cursor);
    scatter_kernel<<<512, 256, 0, stream>>>(ei, etype, E, n, cursor, col);

    // layer 0 (rank-1 input)
    l0h_kernel<<<(n * HCONC + 255) / 256, 256, 0, stream>>>(x, W0s, hb, n);
    l0s_kernel<<<(n * NHEAD + 255) / 256, 256, 0, stream>>>(x, SA0, SD0, ssrc, sdst, n);
    agg_kernel<<<(n + 3) / 4, 256, 0, stream>>>(hb, ssrc, sdst, row_ptr, col,
                                                stab + 0, bias + 0, nullptr, xa, n);
    // layer 1
    transform_kernel<<<(n + 31) / 32, 256, 0, stream>>>(xa, W_l1, att_src + 128, att_dst + 128,
                                                        hb, ssrc, sdst, n);
    agg_kernel<<<(n + 3) / 4, 256, 0, stream>>>(hb, ssrc, sdst, row_ptr, col,
                                                stab + 68, bias + 128, xa, xb, n);
    // layer 2
    transform_kernel<<<(n + 31) / 32, 256, 0, stream>>>(xb, W_l2, att_src + 256, att_dst + 256,
                                                        hb, ssrc, sdst, n);
    agg_kernel<<<(n + 3) / 4, 256, 0, stream>>>(hb, ssrc, sdst, row_ptr, col,
                                                stab + 136, bias + 256, xb, xa, n);
    // MLP head
    mlp_kernel<<<(n + 3) / 4, 128, 0, stream>>>(xa, mW1, mb1, mW2, mb2, (float*)d_out, n);
}